// Round 9
// baseline (165.423 us; speedup 1.0000x reference)
//
#include <hip/hip_runtime.h>

// ---------------------------------------------------------------------------
// GCN pipeline, round 33 (= r32 sort stages unchanged; agg1/agg2 reworked):
//   histA -> scanTilesT -> multisplit2 -> place_fine2 -> agg1_t12 -> agg2_fc.
// r32 lesson: agg2 instruction-shaving is null (2nd null) -- agg2's floor is
// the scattered 64B h2 gather, not instructions. This round removes pure
// overhead instead:
//   (1) agg1: 64 nodes/block as two sequential 32-node groups -- weights
//       (9.6KB) staged ONCE per block: 30MB -> 15MB of redundant L2 weight
//       reads, block count 3125 -> 1563.
//   (2) agg2: drop sidx LDS staging -- 4 lanes/node read the SAME srcs
//       address (HW broadcast, one transaction) and consecutive nodes' CSR
//       ranges are contiguous (L1-resident lines); staging loop + barriers
//       bought nothing. Direct 8-deep-unrolled index loads keep MLP.
// ---------------------------------------------------------------------------

#define MS_TILE 4096
#define MS_T 512
#define MAXB 512  // coarse-bucket count (256 nodes each; NBkt=391 <= 512)
#define AGG_NODES 64
#define PF_T 512   // place_fine2 threads
#define PF_EPT 10  // cached edges/thread (cap 5120/bucket; mean 4096, sd 64)
#define PF_OV 1024 // LDS spill capacity for the (never-expected) overflow

typedef __attribute__((ext_vector_type(4))) _Float16 half4;
typedef __attribute__((ext_vector_type(8))) _Float16 half8;
typedef __attribute__((ext_vector_type(8))) float float8;

// Inclusive shfl scan across 8 waves (512 threads); combine via wsum[8].
__device__ inline int scan512_incl(int v, int lane, int w, int* wsum,
                                   int* total) {
    int incl = v;
#pragma unroll
    for (int d = 1; d < 64; d <<= 1) {
        int up = __shfl_up(incl, d, 64);
        if (lane >= d) incl += up;
    }
    if (lane == 63) wsum[w] = incl;
    __syncthreads();
    int add = 0;
#pragma unroll
    for (int ww = 0; ww < 8; ++ww)
        if (ww < w) add += wsum[ww];
    int tot = 0;
#pragma unroll
    for (int ww = 0; ww < 8; ++ww) tot += wsum[ww];
    *total = tot;
    return incl + add;
}

// per-tile LDS histogram of dst>>8 -> histG[tile*512 + b] (coalesced rows)
__global__ __launch_bounds__(MS_T) void histA(const int* __restrict__ dst,
                                              int* __restrict__ histG, int E) {
    __shared__ int h[MAXB];
    int t = threadIdx.x;
    h[t] = 0;
    __syncthreads();
    int base = blockIdx.x * MS_TILE;
    int cnt = min(MS_TILE, E - base);
    for (int k = t; k < cnt; k += MS_T) atomicAdd(&h[dst[base + k] >> 8], 1);
    __syncthreads();
    histG[blockIdx.x * MAXB + t] = h[t];
}

// Tiled transpose scan: block owns 8 buckets; per 64-tile chunk, load the
// 64x8 sub-panel of histG coalesced, transpose via LDS, shfl-scan each
// bucket in its own wave (register carry), write offsG back coalesced.
__global__ __launch_bounds__(512) void scanTilesT(const int* __restrict__ histG,
                                                  int* __restrict__ offsG,
                                                  int* __restrict__ bucketTotal,
                                                  int nTiles) {
    __shared__ int lds[8][66];
    int t = threadIdx.x;
    int lane = t & 63, w = t >> 6;  // wave w scans bucket B0 + w
    int rr = t >> 3, bb = t & 7;    // load/store mapping (row rr, bucket bb)
    int B0 = blockIdx.x * 8;
    int carry = 0;
    for (int c0 = 0; c0 < nTiles; c0 += 64) {
        int rows = min(64, nTiles - c0);
        int v = 0;
        if (rr < rows) v = histG[(size_t)(c0 + rr) * MAXB + B0 + bb];
        lds[bb][rr] = v;
        __syncthreads();
        int x = lds[w][lane];
        int incl = x;
#pragma unroll
        for (int d = 1; d < 64; d <<= 1) {
            int up = __shfl_up(incl, d, 64);
            if (lane >= d) incl += up;
        }
        int total = __shfl(incl, 63, 64);
        lds[w][lane] = incl - x + carry;  // exclusive prefix + running carry
        carry += total;
        __syncthreads();
        if (rr < rows) offsG[(size_t)(c0 + rr) * MAXB + B0 + bb] = lds[bb][rr];
        __syncthreads();
    }
    if (lane == 0) bucketTotal[B0 + w] = carry;
}

// Deterministic tile counting-sort, 4096-edge tiles @ 512 threads.
// Payload: (src<<8)|(dst&255).
__global__ __launch_bounds__(MS_T) void multisplit2(
    const int* __restrict__ src, const int* __restrict__ dst,
    const int* __restrict__ histG, const int* __restrict__ offsG,
    const int* __restrict__ btot, int* __restrict__ gbaseOut,
    unsigned* __restrict__ binned, int E) {
    __shared__ unsigned stage[MS_TILE];
    __shared__ unsigned short sb[MS_TILE];
    __shared__ int hoff[MAXB + 1];
    __shared__ int hcur[MAXB];
    __shared__ int gb[MAXB];
    __shared__ int wsum[8];
    int t = threadIdx.x;
    int lane = t & 63, w = t >> 6;
    int tile = blockIdx.x;
    int base = tile * MS_TILE;
    int cnt = min(MS_TILE, E - base);

    // bucket-base scan (tile-invariant; one bucket per thread)
    int s2 = btot[t];
    int tot2;
    int incl2 = scan512_incl(s2, lane, w, wsum, &tot2);
    int ex2 = incl2 - s2;
    gb[t] = ex2 + offsG[tile * MAXB + t];
    if (tile == 0) {
        gbaseOut[t] = ex2;
        if (t == MAXB - 1) gbaseOut[MAXB] = E;
    }
    __syncthreads();  // wsum reuse fence

    // tile-local hist scan (one bucket per thread)
    int a0 = histG[tile * MAXB + t];
    int tot;
    int incl = scan512_incl(a0, lane, w, wsum, &tot);
    int ex = incl - a0;
    hoff[t] = ex;
    hcur[t] = ex;
    if (t == MAXB - 1) hoff[MAXB] = cnt;
    __syncthreads();

    for (int k = t; k < cnt; k += MS_T) {
        int d = dst[base + k];
        int b = d >> 8;
        int p = atomicAdd(&hcur[b], 1);
        stage[p] = ((unsigned)src[base + k] << 8) | (unsigned)(d & 255);
        sb[p] = (unsigned short)b;
    }
    __syncthreads();
    for (int k = t; k < cnt; k += MS_T) {
        int b = sb[k];
        binned[gb[b] + (k - hoff[b])] = stage[k];
    }
}

// Per coarse bucket: SINGLE pass over binned (register-cached), first
// atomicAdd doubles as the final intra-node rank. Then shfl scan -> offs,
// dinv, y rows, and an atomic-free register scatter of srcs.
__global__ __launch_bounds__(PF_T) void place_fine2(
    const unsigned* __restrict__ binned, const int* __restrict__ gbase,
    const float* __restrict__ x, int* __restrict__ offs,
    float* __restrict__ dinv, _Float16* __restrict__ y, int* __restrict__ srcs,
    int n) {
    __shared__ int cnt[256];
    __shared__ int baseL[256];
    __shared__ int wsum[8];
    __shared__ unsigned ovW[PF_OV];
    __shared__ int ovR[PF_OV];
    __shared__ int ovN;
    int t = threadIdx.x, b = blockIdx.x;
    int lane = t & 63, w = t >> 6;
    int node0 = b << 8;
    int nn = min(256, n - node0);
    int e0 = gbase[b], e1 = gbase[b + 1];
    if (t < 256) cnt[t] = 0;
    if (t == 0) ovN = 0;
    __syncthreads();

    // pass 1: load + count; the atomic's return value IS the final rank.
    unsigned wdv[PF_EPT];
    int rk[PF_EPT];
    int nc = 0;
#pragma unroll
    for (int u = 0; u < PF_EPT; ++u) {
        int k = e0 + t + u * PF_T;
        if (k < e1) {
            unsigned wd = binned[k];
            wdv[u] = wd;
            rk[u] = atomicAdd(&cnt[wd & 255u], 1);
            nc = u + 1;
        }
    }
    // overflow tail (bucket > PF_EPT*PF_T edges -- never expected; LDS spill)
    for (int k = e0 + t + PF_EPT * PF_T; k < e1; k += PF_T) {
        unsigned wd = binned[k];
        int r = atomicAdd(&cnt[wd & 255u], 1);
        int j = atomicAdd(&ovN, 1);
        if (j < PF_OV) { ovW[j] = wd; ovR[j] = r; }
    }
    __syncthreads();

    // scan counts across the first 4 waves (waves 4..7 carry zeros).
    int c = (t < 256) ? cnt[t] : 0;
    int incl = c;
#pragma unroll
    for (int d = 1; d < 64; d <<= 1) {
        int up = __shfl_up(incl, d, 64);
        if (lane >= d) incl += up;
    }
    if (lane == 63) wsum[w] = incl;
    __syncthreads();
    int add = 0;
    if (w > 0) add += wsum[0];
    if (w > 1) add += wsum[1];
    if (w > 2) add += wsum[2];
    incl += add;
    if (t < 256) {
        int myoff = e0 + incl - c;
        baseL[t] = myoff;
        if (t < nn) {
            int node = node0 + t;
            offs[node] = myoff;
            float di = 1.0f / sqrtf((float)(c + 1));  // +1 self loop
            dinv[node] = di;
            const float* xr = x + (size_t)node * 5;
            half8 hv;
            hv[0] = (_Float16)(xr[0] * di);
            hv[1] = (_Float16)(xr[1] * di);
            hv[2] = (_Float16)(xr[2] * di);
            hv[3] = (_Float16)(xr[3] * di);
            hv[4] = (_Float16)(xr[4] * di);
            hv[5] = (_Float16)0.f;
            hv[6] = (_Float16)0.f;
            hv[7] = (_Float16)0.f;
            *(half8*)(y + (size_t)node * 8) = hv;
        }
    }
    __syncthreads();

    // pass 2: atomic-free scatter from registers.
#pragma unroll
    for (int u = 0; u < PF_EPT; ++u) {
        if (u < nc) {
            unsigned wd = wdv[u];
            srcs[baseL[wd & 255u] + rk[u]] = (int)(wd >> 8);
        }
    }
    int no = min(ovN, PF_OV);
    for (int j = t; j < no; j += PF_T) {
        unsigned wd = ovW[j];
        srcs[baseL[wd & 255u] + ovR[j]] = (int)(wd >> 8);
    }
}

// FUSED layer-1 aggregate + both transforms. 64 nodes/block as TWO
// sequential 32-node groups; weights staged ONCE per block (halves the
// 30MB weight re-staging of the 3125-block version). Per group: gather
// (8 thr/node, 16B half8 loads, shfl-xor reduce), W1, register-tiled W2.
__global__ __launch_bounds__(256) void agg1_t12(
    const _Float16* __restrict__ y, const int* __restrict__ srcs,
    const int* __restrict__ offs, const float* __restrict__ dinv,
    const float* __restrict__ W1, const float* __restrict__ b1,
    const float* __restrict__ W2, _Float16* __restrict__ h2, int n, int E) {
    __shared__ float w1s[320];
    __shared__ float b1s[64];
    __shared__ __align__(16) float w2s[64 * 32];  // [k][g] row-major
    __shared__ __align__(16) float o1[32 * 68];   // row padded to 68 floats
    __shared__ float zs[32 * 6];
    int t = threadIdx.x;
    w1s[t] = W1[t];
    if (t < 64) {
        w1s[t + 256] = W1[t + 256];
        b1s[t] = b1[t];
    }
#pragma unroll
    for (int r = 0; r < 8; ++r) w2s[r * 256 + t] = W2[r * 256 + t];

    const half8* yv = (const half8*)y;
    int li = t >> 3, e = t & 7;

    for (int g = 0; g < 2; ++g) {
        int node0 = blockIdx.x * 64 + g * 32;
        if (g) __syncthreads();  // protect zs/o1 from previous group's W2
        int i = node0 + li;
        float a0 = 0.f, a1 = 0.f, a2 = 0.f, a3 = 0.f, a4 = 0.f;
        if (i < n) {
            int off = offs[i];
            int cnt = ((i + 1 < n) ? offs[i + 1] : E) - off;
            if (e == 0) {  // self-loop term once per node
                half8 v = yv[i];
                a0 = (float)v[0]; a1 = (float)v[1]; a2 = (float)v[2];
                a3 = (float)v[3]; a4 = (float)v[4];
            }
            for (int p = e; p < cnt; p += 8) {
                half8 v = yv[srcs[off + p]];
                a0 += (float)v[0]; a1 += (float)v[1]; a2 += (float)v[2];
                a3 += (float)v[3]; a4 += (float)v[4];
            }
        }
#pragma unroll
        for (int m = 4; m >= 1; m >>= 1) {
            a0 += __shfl_xor(a0, m, 64);
            a1 += __shfl_xor(a1, m, 64);
            a2 += __shfl_xor(a2, m, 64);
            a3 += __shfl_xor(a3, m, 64);
            a4 += __shfl_xor(a4, m, 64);
        }
        if (i < n && e == 0) {
            float di = dinv[i];
            zs[li * 6 + 0] = a0 * di;
            zs[li * 6 + 1] = a1 * di;
            zs[li * 6 + 2] = a2 * di;
            zs[li * 6 + 3] = a3 * di;
            zs[li * 6 + 4] = a4 * di;
            zs[li * 6 + 5] = di;
        }
        __syncthreads();
        // W1 phase: o1[j][f] = relu(z_j . W1[:,f] + b1[f]) into padded rows.
#pragma unroll
        for (int r = 0; r < 8; ++r) {
            int idx = r * 256 + t;
            int lj = idx >> 6, f = idx & 63;
            if (node0 + lj < n) {
                const float* zr = zs + lj * 6;
                float acc = b1s[f];
#pragma unroll
                for (int k = 0; k < 5; ++k) acc += zr[k] * w1s[k * 64 + f];
                o1[lj * 68 + f] = fmaxf(acc, 0.0f);
            }
        }
        __syncthreads();
        // W2 phase: thread = (node j, outputs g0..g0+3), all-b128 LDS reads.
        {
            int j = t >> 3;         // node 0..31
            int g0 = (t & 7) << 2;  // output 0,4,...,28
            const float* o1r = o1 + j * 68;
            float acc0 = 0.f, acc1 = 0.f, acc2 = 0.f, acc3 = 0.f;
#pragma unroll
            for (int k4 = 0; k4 < 64; k4 += 4) {
                float4 ov = *(const float4*)(o1r + k4);
                float4 w0 = *(const float4*)(w2s + (k4 + 0) * 32 + g0);
                float4 w1v = *(const float4*)(w2s + (k4 + 1) * 32 + g0);
                float4 w2v = *(const float4*)(w2s + (k4 + 2) * 32 + g0);
                float4 w3v = *(const float4*)(w2s + (k4 + 3) * 32 + g0);
                acc0 += ov.x * w0.x + ov.y * w1v.x + ov.z * w2v.x + ov.w * w3v.x;
                acc1 += ov.x * w0.y + ov.y * w1v.y + ov.z * w2v.y + ov.w * w3v.y;
                acc2 += ov.x * w0.z + ov.y * w1v.z + ov.z * w2v.z + ov.w * w3v.z;
                acc3 += ov.x * w0.w + ov.y * w1v.w + ov.z * w2v.w + ov.w * w3v.w;
            }
            int i2 = node0 + j;
            if (i2 < n) {
                float di = zs[j * 6 + 5];
                half4 hv;
                hv.x = (_Float16)(acc0 * di);
                hv.y = (_Float16)(acc1 * di);
                hv.z = (_Float16)(acc2 * di);
                hv.w = (_Float16)(acc3 * di);
                *(half4*)(h2 + (size_t)i2 * 32 + g0) = hv;  // coalesced 8B
            }
        }
    }
}

// FUSED layer-2 aggregate + FC head, 64-node blocks (1563 blocks).
// Gather: 4 threads/node x half8 (16B); srcs indices read DIRECTLY from
// global (4 lanes same addr = HW broadcast; consecutive nodes' CSR ranges
// contiguous = L1-resident) -- no LDS staging, no staging barriers.
// FC1 register-tiled (node, 4 of 16 outputs) all-b128.
__global__ __launch_bounds__(256) void agg2_fc(
    const _Float16* __restrict__ h, const int* __restrict__ srcs,
    const int* __restrict__ offs, const float* __restrict__ dinv,
    const float* __restrict__ b2, const float* __restrict__ fcW1,
    const float* __restrict__ fcb1, const float* __restrict__ fcW2,
    const float* __restrict__ fcb2, float* __restrict__ out, int n, int E) {
    __shared__ __align__(16) float sm[AGG_NODES * 36];   // row stride 36
    __shared__ __align__(16) float x3s[AGG_NODES * 20];  // row stride 20
    __shared__ __align__(16) float w1s[512];             // fcW1 [32][16]
    __shared__ float w2s[32];
    __shared__ float b1s[16];
    __shared__ float b2s[2];
    __shared__ float bs2[32];
    int t = threadIdx.x;
    w1s[t] = fcW1[t];
    w1s[t + 256] = fcW1[t + 256];
    if (t < 32) { w2s[t] = fcW2[t]; bs2[t] = b2[t]; }
    if (t < 16) b1s[t] = fcb1[t];
    if (t < 2) b2s[t] = fcb2[t];

    int node0 = blockIdx.x * AGG_NODES;
    int li = t >> 2, fq = t & 3;  // 4 threads/node, 64 nodes
    int i = node0 + li;
    bool live = (i < n);
    const char* hb = (const char*)h;

    if (live) {
        int myOff = offs[i];
        int myCnt = ((i + 1 < n) ? offs[i + 1] : E) - myOff;
        float8 acc;
        half8 sv = *(const half8*)(hb + ((size_t)i << 6) + (fq << 4));
#pragma unroll
        for (int j = 0; j < 8; ++j) acc[j] = (float)sv[j];

        const int* sp = srcs + myOff;
        int p = 0;
        for (; p + 8 <= myCnt; p += 8) {
            int o[8];
#pragma unroll
            for (int u = 0; u < 8; ++u) o[u] = sp[p + u] << 6;
            half8 v[8];
#pragma unroll
            for (int u = 0; u < 8; ++u)
                v[u] = *(const half8*)(hb + o[u] + (fq << 4));
#pragma unroll
            for (int u = 0; u < 8; ++u) {
#pragma unroll
                for (int j = 0; j < 8; ++j) acc[j] += (float)v[u][j];
            }
        }
        for (; p < myCnt; ++p) {
            half8 v = *(const half8*)(hb + (sp[p] << 6) + (fq << 4));
#pragma unroll
            for (int j = 0; j < 8; ++j) acc[j] += (float)v[j];
        }

        float di = dinv[i];
        int f0 = fq << 3;
#pragma unroll
        for (int j = 0; j < 8; ++j)
            sm[li * 36 + f0 + j] = fmaxf(di * acc[j] + bs2[f0 + j], 0.f);
    }
    __syncthreads();
    // FC1 register-tiled: thread = (node j, outputs g0..g0+3), all-b128.
    {
        int j = t >> 2;          // node 0..63
        int g0 = (t & 3) << 2;   // output 0,4,8,12
        const float* smr = sm + j * 36;
        float a0 = 0.f, a1 = 0.f, a2 = 0.f, a3 = 0.f;
#pragma unroll
        for (int k4 = 0; k4 < 32; k4 += 4) {
            float4 sv = *(const float4*)(smr + k4);
            float4 w0 = *(const float4*)(w1s + (k4 + 0) * 16 + g0);
            float4 w1v = *(const float4*)(w1s + (k4 + 1) * 16 + g0);
            float4 w2v = *(const float4*)(w1s + (k4 + 2) * 16 + g0);
            float4 w3v = *(const float4*)(w1s + (k4 + 3) * 16 + g0);
            a0 += sv.x * w0.x + sv.y * w1v.x + sv.z * w2v.x + sv.w * w3v.x;
            a1 += sv.x * w0.y + sv.y * w1v.y + sv.z * w2v.y + sv.w * w3v.y;
            a2 += sv.x * w0.z + sv.y * w1v.z + sv.z * w2v.z + sv.w * w3v.z;
            a3 += sv.x * w0.w + sv.y * w1v.w + sv.z * w2v.w + sv.w * w3v.w;
        }
        if (node0 + j < n) {
            x3s[j * 20 + g0 + 0] = fmaxf(a0 + b1s[g0 + 0], 0.f);
            x3s[j * 20 + g0 + 1] = fmaxf(a1 + b1s[g0 + 1], 0.f);
            x3s[j * 20 + g0 + 2] = fmaxf(a2 + b1s[g0 + 2], 0.f);
            x3s[j * 20 + g0 + 3] = fmaxf(a3 + b1s[g0 + 3], 0.f);
        }
    }
    __syncthreads();
    if (t < 128) {
        int lj = t >> 1, o = t & 1;
        if (node0 + lj < n) {
            float a = b2s[o];
#pragma unroll
            for (int j = 0; j < 16; ++j) a += x3s[lj * 20 + j] * w2s[j * 2 + o];
            out[(size_t)(node0 + lj) * 2 + o] = a;
        }
    }
}

extern "C" void kernel_launch(void* const* d_in, const int* in_sizes, int n_in,
                              void* d_out, int out_size, void* d_ws, size_t ws_size,
                              hipStream_t stream) {
    const float* edge_attr = (const float*)d_in[0];
    const int* edge_index  = (const int*)d_in[1];
    const float* W1   = (const float*)d_in[2];
    const float* b1   = (const float*)d_in[3];
    const float* W2   = (const float*)d_in[4];
    const float* b2   = (const float*)d_in[5];
    const float* fcW1 = (const float*)d_in[6];
    const float* fcb1 = (const float*)d_in[7];
    const float* fcW2 = (const float*)d_in[8];
    const float* fcb2 = (const float*)d_in[9];
    float* out = (float*)d_out;

    int n = in_sizes[0] / 5;
    int E = in_sizes[1] / 2;
    int NBkt = (n + 255) >> 8;                 // 391 for n=100000 (<= MAXB)
    int nTiles = (E + MS_TILE - 1) / MS_TILE;  // 391 at E=1.6M
    const int* src = edge_index;
    const int* dst = edge_index + E;

    char* ws = (char*)d_ws;
    auto alloc = [&](size_t bytes) {
        char* p = ws;
        ws += (bytes + 255) & ~(size_t)255;
        return p;
    };
    int*      offs   = (int*)alloc((size_t)n * 4);
    float*    dinv   = (float*)alloc((size_t)n * 4);
    int*      histG  = (int*)alloc((size_t)nTiles * MAXB * 4);
    int*      offsG  = (int*)alloc((size_t)nTiles * MAXB * 4);
    int*      btot   = (int*)alloc((size_t)MAXB * 4);
    int*      gbase  = (int*)alloc((size_t)(MAXB + 1) * 4);
    int*      srcs   = (int*)alloc((size_t)E * 4);
    unsigned* binned = (unsigned*)alloc((size_t)E * 4);
    _Float16* y      = (_Float16*)alloc((size_t)n * 8 * 2);
    _Float16* h2     = (_Float16*)alloc((size_t)n * 32 * 2);

    histA<<<nTiles, MS_T, 0, stream>>>(dst, histG, E);
    scanTilesT<<<MAXB / 8, 512, 0, stream>>>(histG, offsG, btot, nTiles);
    multisplit2<<<nTiles, MS_T, 0, stream>>>(src, dst, histG, offsG, btot,
                                             gbase, binned, E);
    place_fine2<<<NBkt, PF_T, 0, stream>>>(binned, gbase, edge_attr, offs, dinv,
                                           y, srcs, n);
    agg1_t12<<<(n + 63) / 64, 256, 0, stream>>>(y, srcs, offs, dinv, W1, b1, W2,
                                                h2, n, E);
    agg2_fc<<<(n + AGG_NODES - 1) / AGG_NODES, 256, 0, stream>>>(
        h2, srcs, offs, dinv, b2, fcW1, fcb1, fcW2, fcb2, out, n, E);
}

// Round 10
// 161.549 us; speedup vs baseline: 1.0240x; 1.0240x over previous
//
#include <hip/hip_runtime.h>

// ---------------------------------------------------------------------------
// GCN pipeline, round 34 = round 31 VERBATIM (session best, 162.7us).
// r32 (agg2 instr-shaving, +1us) and r33 (staging-overhead removal, +2.7us)
// both measured null-to-negative -> reverted. The pipeline is at its
// practical plateau: 6 truly-dependent dispatches (each stage needs the
// previous stage's GLOBAL output; fusion requires grid sync = 100s of us on
// 8 XCDs), each latency-bound on scattered gathers / launch floors, with
// essential traffic (~123MB ~= 20us) far below the measured 163us.
// Verified wins: 4096-edge sort tiles (r30, -4us) + register-tiled b128 W2
// in agg1 (r31, -10.5us). Verified dead ends: global atomics (r29, +55us),
// cooperative mega-kernel (r27, +800us), traffic/instruction shaving in
// agg2 (r32/r33, null).
// ---------------------------------------------------------------------------

#define MS_TILE 4096
#define MS_T 512
#define MAXB 512  // coarse-bucket count (256 nodes each; NBkt=391 <= 512)
#define AGG_NODES 32
#define AGG_STAGE 1024
#define PF_T 512   // place_fine2 threads
#define PF_EPT 10  // cached edges/thread (cap 5120/bucket; mean 4096, sd 64)
#define PF_OV 1024 // LDS spill capacity for the (never-expected) overflow

typedef __attribute__((ext_vector_type(4))) _Float16 half4;
typedef __attribute__((ext_vector_type(8))) _Float16 half8;

// Inclusive shfl scan across 8 waves (512 threads); combine via wsum[8].
__device__ inline int scan512_incl(int v, int lane, int w, int* wsum,
                                   int* total) {
    int incl = v;
#pragma unroll
    for (int d = 1; d < 64; d <<= 1) {
        int up = __shfl_up(incl, d, 64);
        if (lane >= d) incl += up;
    }
    if (lane == 63) wsum[w] = incl;
    __syncthreads();
    int add = 0;
#pragma unroll
    for (int ww = 0; ww < 8; ++ww)
        if (ww < w) add += wsum[ww];
    int tot = 0;
#pragma unroll
    for (int ww = 0; ww < 8; ++ww) tot += wsum[ww];
    *total = tot;
    return incl + add;
}

// per-tile LDS histogram of dst>>8 -> histG[tile*512 + b] (coalesced rows)
__global__ __launch_bounds__(MS_T) void histA(const int* __restrict__ dst,
                                              int* __restrict__ histG, int E) {
    __shared__ int h[MAXB];
    int t = threadIdx.x;
    h[t] = 0;
    __syncthreads();
    int base = blockIdx.x * MS_TILE;
    int cnt = min(MS_TILE, E - base);
    for (int k = t; k < cnt; k += MS_T) atomicAdd(&h[dst[base + k] >> 8], 1);
    __syncthreads();
    histG[blockIdx.x * MAXB + t] = h[t];
}

// Tiled transpose scan: block owns 8 buckets; per 64-tile chunk, load the
// 64x8 sub-panel of histG coalesced, transpose via LDS, shfl-scan each
// bucket in its own wave (register carry), write offsG back coalesced.
__global__ __launch_bounds__(512) void scanTilesT(const int* __restrict__ histG,
                                                  int* __restrict__ offsG,
                                                  int* __restrict__ bucketTotal,
                                                  int nTiles) {
    __shared__ int lds[8][66];
    int t = threadIdx.x;
    int lane = t & 63, w = t >> 6;  // wave w scans bucket B0 + w
    int rr = t >> 3, bb = t & 7;    // load/store mapping (row rr, bucket bb)
    int B0 = blockIdx.x * 8;
    int carry = 0;
    for (int c0 = 0; c0 < nTiles; c0 += 64) {
        int rows = min(64, nTiles - c0);
        int v = 0;
        if (rr < rows) v = histG[(size_t)(c0 + rr) * MAXB + B0 + bb];
        lds[bb][rr] = v;
        __syncthreads();
        int x = lds[w][lane];
        int incl = x;
#pragma unroll
        for (int d = 1; d < 64; d <<= 1) {
            int up = __shfl_up(incl, d, 64);
            if (lane >= d) incl += up;
        }
        int total = __shfl(incl, 63, 64);
        lds[w][lane] = incl - x + carry;  // exclusive prefix + running carry
        carry += total;
        __syncthreads();
        if (rr < rows) offsG[(size_t)(c0 + rr) * MAXB + B0 + bb] = lds[bb][rr];
        __syncthreads();
    }
    if (lane == 0) bucketTotal[B0 + w] = carry;
}

// Deterministic tile counting-sort, 4096-edge tiles @ 512 threads.
// Payload: (src<<8)|(dst&255).
__global__ __launch_bounds__(MS_T) void multisplit2(
    const int* __restrict__ src, const int* __restrict__ dst,
    const int* __restrict__ histG, const int* __restrict__ offsG,
    const int* __restrict__ btot, int* __restrict__ gbaseOut,
    unsigned* __restrict__ binned, int E) {
    __shared__ unsigned stage[MS_TILE];
    __shared__ unsigned short sb[MS_TILE];
    __shared__ int hoff[MAXB + 1];
    __shared__ int hcur[MAXB];
    __shared__ int gb[MAXB];
    __shared__ int wsum[8];
    int t = threadIdx.x;
    int lane = t & 63, w = t >> 6;
    int tile = blockIdx.x;
    int base = tile * MS_TILE;
    int cnt = min(MS_TILE, E - base);

    // bucket-base scan (tile-invariant; one bucket per thread)
    int s2 = btot[t];
    int tot2;
    int incl2 = scan512_incl(s2, lane, w, wsum, &tot2);
    int ex2 = incl2 - s2;
    gb[t] = ex2 + offsG[tile * MAXB + t];
    if (tile == 0) {
        gbaseOut[t] = ex2;
        if (t == MAXB - 1) gbaseOut[MAXB] = E;
    }
    __syncthreads();  // wsum reuse fence

    // tile-local hist scan (one bucket per thread)
    int a0 = histG[tile * MAXB + t];
    int tot;
    int incl = scan512_incl(a0, lane, w, wsum, &tot);
    int ex = incl - a0;
    hoff[t] = ex;
    hcur[t] = ex;
    if (t == MAXB - 1) hoff[MAXB] = cnt;
    __syncthreads();

    for (int k = t; k < cnt; k += MS_T) {
        int d = dst[base + k];
        int b = d >> 8;
        int p = atomicAdd(&hcur[b], 1);
        stage[p] = ((unsigned)src[base + k] << 8) | (unsigned)(d & 255);
        sb[p] = (unsigned short)b;
    }
    __syncthreads();
    for (int k = t; k < cnt; k += MS_T) {
        int b = sb[k];
        binned[gb[b] + (k - hoff[b])] = stage[k];
    }
}

// Per coarse bucket: SINGLE pass over binned (register-cached), first
// atomicAdd doubles as the final intra-node rank. Then shfl scan -> offs,
// dinv, y rows, and an atomic-free register scatter of srcs.
__global__ __launch_bounds__(PF_T) void place_fine2(
    const unsigned* __restrict__ binned, const int* __restrict__ gbase,
    const float* __restrict__ x, int* __restrict__ offs,
    float* __restrict__ dinv, _Float16* __restrict__ y, int* __restrict__ srcs,
    int n) {
    __shared__ int cnt[256];
    __shared__ int baseL[256];
    __shared__ int wsum[8];
    __shared__ unsigned ovW[PF_OV];
    __shared__ int ovR[PF_OV];
    __shared__ int ovN;
    int t = threadIdx.x, b = blockIdx.x;
    int lane = t & 63, w = t >> 6;
    int node0 = b << 8;
    int nn = min(256, n - node0);
    int e0 = gbase[b], e1 = gbase[b + 1];
    if (t < 256) cnt[t] = 0;
    if (t == 0) ovN = 0;
    __syncthreads();

    // pass 1: load + count; the atomic's return value IS the final rank.
    unsigned wdv[PF_EPT];
    int rk[PF_EPT];
    int nc = 0;
#pragma unroll
    for (int u = 0; u < PF_EPT; ++u) {
        int k = e0 + t + u * PF_T;
        if (k < e1) {
            unsigned wd = binned[k];
            wdv[u] = wd;
            rk[u] = atomicAdd(&cnt[wd & 255u], 1);
            nc = u + 1;
        }
    }
    // overflow tail (bucket > PF_EPT*PF_T edges -- never expected; LDS spill)
    for (int k = e0 + t + PF_EPT * PF_T; k < e1; k += PF_T) {
        unsigned wd = binned[k];
        int r = atomicAdd(&cnt[wd & 255u], 1);
        int j = atomicAdd(&ovN, 1);
        if (j < PF_OV) { ovW[j] = wd; ovR[j] = r; }
    }
    __syncthreads();

    // scan counts across the first 4 waves (waves 4..7 carry zeros).
    int c = (t < 256) ? cnt[t] : 0;
    int incl = c;
#pragma unroll
    for (int d = 1; d < 64; d <<= 1) {
        int up = __shfl_up(incl, d, 64);
        if (lane >= d) incl += up;
    }
    if (lane == 63) wsum[w] = incl;
    __syncthreads();
    int add = 0;
    if (w > 0) add += wsum[0];
    if (w > 1) add += wsum[1];
    if (w > 2) add += wsum[2];
    incl += add;
    if (t < 256) {
        int myoff = e0 + incl - c;
        baseL[t] = myoff;
        if (t < nn) {
            int node = node0 + t;
            offs[node] = myoff;
            float di = 1.0f / sqrtf((float)(c + 1));  // +1 self loop
            dinv[node] = di;
            const float* xr = x + (size_t)node * 5;
            half8 hv;
            hv[0] = (_Float16)(xr[0] * di);
            hv[1] = (_Float16)(xr[1] * di);
            hv[2] = (_Float16)(xr[2] * di);
            hv[3] = (_Float16)(xr[3] * di);
            hv[4] = (_Float16)(xr[4] * di);
            hv[5] = (_Float16)0.f;
            hv[6] = (_Float16)0.f;
            hv[7] = (_Float16)0.f;
            *(half8*)(y + (size_t)node * 8) = hv;
        }
    }
    __syncthreads();

    // pass 2: atomic-free scatter from registers.
#pragma unroll
    for (int u = 0; u < PF_EPT; ++u) {
        if (u < nc) {
            unsigned wd = wdv[u];
            srcs[baseL[wd & 255u] + rk[u]] = (int)(wd >> 8);
        }
    }
    int no = min(ovN, PF_OV);
    for (int j = t; j < no; j += PF_T) {
        unsigned wd = ovW[j];
        srcs[baseL[wd & 255u] + ovR[j]] = (int)(wd >> 8);
    }
}

// FUSED layer-1 aggregate + both transforms, 32-node blocks (3125 blocks).
// Gather: 8 threads/node, ONE 16B half8 load per edge, fp32 accumulate,
// shfl-xor reduce; z in LDS. W2 phase: register-tiled (1 node x 4 outputs
// per thread), all-b128 LDS reads, coalesced half4 h2 stores.
__global__ __launch_bounds__(256) void agg1_t12(
    const _Float16* __restrict__ y, const int* __restrict__ srcs,
    const int* __restrict__ offs, const float* __restrict__ dinv,
    const float* __restrict__ W1, const float* __restrict__ b1,
    const float* __restrict__ W2, _Float16* __restrict__ h2, int n, int E) {
    __shared__ float w1s[320];
    __shared__ float b1s[64];
    __shared__ __align__(16) float w2s[64 * 32];  // [k][g] row-major
    __shared__ __align__(16) float o1[32 * 68];   // row padded to 68 floats
    __shared__ float zs[32 * 6];
    int t = threadIdx.x;
    w1s[t] = W1[t];
    if (t < 64) {
        w1s[t + 256] = W1[t + 256];
        b1s[t] = b1[t];
    }
#pragma unroll
    for (int r = 0; r < 8; ++r) w2s[r * 256 + t] = W2[r * 256 + t];

    int node0 = blockIdx.x * 32;
    int li = t >> 3, e = t & 7;
    int i = node0 + li;
    const half8* yv = (const half8*)y;
    float a0 = 0.f, a1 = 0.f, a2 = 0.f, a3 = 0.f, a4 = 0.f;
    if (i < n) {
        int off = offs[i];
        int cnt = ((i + 1 < n) ? offs[i + 1] : E) - off;
        if (e == 0) {  // self-loop term once per node
            half8 v = yv[i];
            a0 = (float)v[0]; a1 = (float)v[1]; a2 = (float)v[2];
            a3 = (float)v[3]; a4 = (float)v[4];
        }
        for (int p = e; p < cnt; p += 8) {
            half8 v = yv[srcs[off + p]];
            a0 += (float)v[0]; a1 += (float)v[1]; a2 += (float)v[2];
            a3 += (float)v[3]; a4 += (float)v[4];
        }
    }
#pragma unroll
    for (int m = 4; m >= 1; m >>= 1) {
        a0 += __shfl_xor(a0, m, 64);
        a1 += __shfl_xor(a1, m, 64);
        a2 += __shfl_xor(a2, m, 64);
        a3 += __shfl_xor(a3, m, 64);
        a4 += __shfl_xor(a4, m, 64);
    }
    if (i < n && e == 0) {
        float di = dinv[i];
        zs[li * 6 + 0] = a0 * di;
        zs[li * 6 + 1] = a1 * di;
        zs[li * 6 + 2] = a2 * di;
        zs[li * 6 + 3] = a3 * di;
        zs[li * 6 + 4] = a4 * di;
        zs[li * 6 + 5] = di;
    }
    __syncthreads();
    // W1 phase: o1[j][f] = relu(z_j . W1[:,f] + b1[f]) into padded rows.
#pragma unroll
    for (int r = 0; r < 8; ++r) {
        int idx = r * 256 + t;
        int lj = idx >> 6, f = idx & 63;
        if (node0 + lj < n) {
            const float* zr = zs + lj * 6;
            float acc = b1s[f];
#pragma unroll
            for (int k = 0; k < 5; ++k) acc += zr[k] * w1s[k * 64 + f];
            o1[lj * 68 + f] = fmaxf(acc, 0.0f);
        }
    }
    __syncthreads();
    // W2 phase: thread = (node j, outputs g0..g0+3), all-b128 LDS reads.
    {
        int j = t >> 3;            // node 0..31
        int g0 = (t & 7) << 2;     // output 0,4,...,28
        const float* o1r = o1 + j * 68;
        float acc0 = 0.f, acc1 = 0.f, acc2 = 0.f, acc3 = 0.f;
#pragma unroll
        for (int k4 = 0; k4 < 64; k4 += 4) {
            float4 ov = *(const float4*)(o1r + k4);
            float4 w0 = *(const float4*)(w2s + (k4 + 0) * 32 + g0);
            float4 w1v = *(const float4*)(w2s + (k4 + 1) * 32 + g0);
            float4 w2v = *(const float4*)(w2s + (k4 + 2) * 32 + g0);
            float4 w3v = *(const float4*)(w2s + (k4 + 3) * 32 + g0);
            acc0 += ov.x * w0.x + ov.y * w1v.x + ov.z * w2v.x + ov.w * w3v.x;
            acc1 += ov.x * w0.y + ov.y * w1v.y + ov.z * w2v.y + ov.w * w3v.y;
            acc2 += ov.x * w0.z + ov.y * w1v.z + ov.z * w2v.z + ov.w * w3v.z;
            acc3 += ov.x * w0.w + ov.y * w1v.w + ov.z * w2v.w + ov.w * w3v.w;
        }
        int i2 = node0 + j;
        if (i2 < n) {
            float di = zs[j * 6 + 5];
            half4 hv;
            hv.x = (_Float16)(acc0 * di);
            hv.y = (_Float16)(acc1 * di);
            hv.z = (_Float16)(acc2 * di);
            hv.w = (_Float16)(acc3 * di);
            *(half4*)(h2 + (size_t)i2 * 32 + g0) = hv;  // coalesced 8B store
        }
    }
}

// FUSED layer-2 aggregate + FC head. fp16 h2 rows (64B), 8 threads/node
// each gathering 8B (half4); fp32 accumulation; LDS-staged CSR indices.
__global__ __launch_bounds__(256) void agg2_fc(
    const _Float16* __restrict__ h, const int* __restrict__ srcs,
    const int* __restrict__ offs, const float* __restrict__ dinv,
    const float* __restrict__ b2, const float* __restrict__ fcW1,
    const float* __restrict__ fcb1, const float* __restrict__ fcW2,
    const float* __restrict__ fcb2, float* __restrict__ out, int n, int E) {
    __shared__ int sidx[AGG_STAGE];
    __shared__ float sm[AGG_NODES * 33];
    __shared__ float x3s[AGG_NODES * 16];
    __shared__ float w1s[512];
    __shared__ float w2s[32];
    __shared__ float b1s[16];
    __shared__ float b2s[2];
    __shared__ float bs2[32];
    int t = threadIdx.x;
    w1s[t] = fcW1[t];
    w1s[t + 256] = fcW1[t + 256];
    if (t < 32) { w2s[t] = fcW2[t]; bs2[t] = b2[t]; }
    if (t < 16) b1s[t] = fcb1[t];
    if (t < 2) b2s[t] = fcb2[t];

    int node0 = blockIdx.x * AGG_NODES;
    int li = t >> 3, fq = t & 7;
    int i = node0 + li;
    bool live = (i < n);
    const char* hb = (const char*)h;

    int e0 = offs[node0];
    int eEnd = (node0 + AGG_NODES < n) ? offs[node0 + AGG_NODES] : E;
    int myOff = 0, myCnt = 0;
    float4 acc = {0.f, 0.f, 0.f, 0.f};
    if (live) {
        myOff = offs[i];
        myCnt = ((i + 1 < n) ? offs[i + 1] : E) - myOff;
        half4 sv = *(const half4*)(hb + ((size_t)i << 6) + (fq << 3));
        acc.x = (float)sv.x; acc.y = (float)sv.y;
        acc.z = (float)sv.z; acc.w = (float)sv.w;
    }

    for (int cs = e0; cs < eEnd; cs += AGG_STAGE) {
        int ce = min(cs + AGG_STAGE, eEnd);
        for (int k = cs + t; k < ce; k += 256) sidx[k - cs] = srcs[k] << 6;
        __syncthreads();
        int ps = max(myOff, cs), pe = min(myOff + myCnt, ce);
        int p = ps;
        for (; p + 8 <= pe; p += 8) {
            int o[8];
#pragma unroll
            for (int u = 0; u < 8; ++u) o[u] = sidx[p + u - cs];
            half4 v[8];
#pragma unroll
            for (int u = 0; u < 8; ++u)
                v[u] = *(const half4*)(hb + o[u] + (fq << 3));
#pragma unroll
            for (int u = 0; u < 8; ++u) {
                acc.x += (float)v[u].x; acc.y += (float)v[u].y;
                acc.z += (float)v[u].z; acc.w += (float)v[u].w;
            }
        }
        for (; p + 4 <= pe; p += 4) {
            int o0 = sidx[p - cs], o1 = sidx[p + 1 - cs];
            int o2 = sidx[p + 2 - cs], o3 = sidx[p + 3 - cs];
            half4 v0 = *(const half4*)(hb + o0 + (fq << 3));
            half4 v1 = *(const half4*)(hb + o1 + (fq << 3));
            half4 v2 = *(const half4*)(hb + o2 + (fq << 3));
            half4 v3 = *(const half4*)(hb + o3 + (fq << 3));
            acc.x += (float)v0.x + (float)v1.x + (float)v2.x + (float)v3.x;
            acc.y += (float)v0.y + (float)v1.y + (float)v2.y + (float)v3.y;
            acc.z += (float)v0.z + (float)v1.z + (float)v2.z + (float)v3.z;
            acc.w += (float)v0.w + (float)v1.w + (float)v2.w + (float)v3.w;
        }
        for (; p < pe; ++p) {
            half4 v = *(const half4*)(hb + sidx[p - cs] + (fq << 3));
            acc.x += (float)v.x; acc.y += (float)v.y;
            acc.z += (float)v.z; acc.w += (float)v.w;
        }
        __syncthreads();
    }

    if (live) {
        float di = dinv[i];
        int f0 = fq << 2;
        sm[li * 33 + f0 + 0] = fmaxf(di * acc.x + bs2[f0 + 0], 0.f);
        sm[li * 33 + f0 + 1] = fmaxf(di * acc.y + bs2[f0 + 1], 0.f);
        sm[li * 33 + f0 + 2] = fmaxf(di * acc.z + bs2[f0 + 2], 0.f);
        sm[li * 33 + f0 + 3] = fmaxf(di * acc.w + bs2[f0 + 3], 0.f);
    }
    __syncthreads();
#pragma unroll
    for (int r = 0; r < 2; ++r) {
        int idx = r * 256 + t;
        int lj = idx >> 4, j = idx & 15;
        if (node0 + lj < n) {
            float a = b1s[j];
#pragma unroll
            for (int k = 0; k < 32; ++k) a += sm[lj * 33 + k] * w1s[k * 16 + j];
            x3s[lj * 16 + j] = fmaxf(a, 0.f);
        }
    }
    __syncthreads();
    if (t < 64) {
        int lj = t >> 1, o = t & 1;
        if (node0 + lj < n) {
            float a = b2s[o];
#pragma unroll
            for (int j = 0; j < 16; ++j) a += x3s[lj * 16 + j] * w2s[j * 2 + o];
            out[(size_t)(node0 + lj) * 2 + o] = a;
        }
    }
}

extern "C" void kernel_launch(void* const* d_in, const int* in_sizes, int n_in,
                              void* d_out, int out_size, void* d_ws, size_t ws_size,
                              hipStream_t stream) {
    const float* edge_attr = (const float*)d_in[0];
    const int* edge_index  = (const int*)d_in[1];
    const float* W1   = (const float*)d_in[2];
    const float* b1   = (const float*)d_in[3];
    const float* W2   = (const float*)d_in[4];
    const float* b2   = (const float*)d_in[5];
    const float* fcW1 = (const float*)d_in[6];
    const float* fcb1 = (const float*)d_in[7];
    const float* fcW2 = (const float*)d_in[8];
    const float* fcb2 = (const float*)d_in[9];
    float* out = (float*)d_out;

    int n = in_sizes[0] / 5;
    int E = in_sizes[1] / 2;
    int NBkt = (n + 255) >> 8;                 // 391 for n=100000 (<= MAXB)
    int nTiles = (E + MS_TILE - 1) / MS_TILE;  // 391 at E=1.6M
    const int* src = edge_index;
    const int* dst = edge_index + E;

    char* ws = (char*)d_ws;
    auto alloc = [&](size_t bytes) {
        char* p = ws;
        ws += (bytes + 255) & ~(size_t)255;
        return p;
    };
    int*      offs   = (int*)alloc((size_t)n * 4);
    float*    dinv   = (float*)alloc((size_t)n * 4);
    int*      histG  = (int*)alloc((size_t)nTiles * MAXB * 4);
    int*      offsG  = (int*)alloc((size_t)nTiles * MAXB * 4);
    int*      btot   = (int*)alloc((size_t)MAXB * 4);
    int*      gbase  = (int*)alloc((size_t)(MAXB + 1) * 4);
    int*      srcs   = (int*)alloc((size_t)E * 4);
    unsigned* binned = (unsigned*)alloc((size_t)E * 4);
    _Float16* y      = (_Float16*)alloc((size_t)n * 8 * 2);
    _Float16* h2     = (_Float16*)alloc((size_t)n * 32 * 2);

    histA<<<nTiles, MS_T, 0, stream>>>(dst, histG, E);
    scanTilesT<<<MAXB / 8, 512, 0, stream>>>(histG, offsG, btot, nTiles);
    multisplit2<<<nTiles, MS_T, 0, stream>>>(src, dst, histG, offsG, btot,
                                             gbase, binned, E);
    place_fine2<<<NBkt, PF_T, 0, stream>>>(binned, gbase, edge_attr, offs, dinv,
                                           y, srcs, n);
    agg1_t12<<<(n + 31) / 32, 256, 0, stream>>>(y, srcs, offs, dinv, W1, b1, W2,
                                                h2, n, E);
    agg2_fc<<<(n + AGG_NODES - 1) / AGG_NODES, 256, 0, stream>>>(
        h2, srcs, offs, dinv, b2, fcW1, fcb1, fcW2, fcb2, out, n, E);
}